// Round 12
// baseline (159.115 us; speedup 1.0000x reference)
//
#include <hip/hip_runtime.h>
#include <hip/hip_bf16.h>
#include <math.h>

#define NS 2048
#define NR 512
#define ND 64
#define NH 8
#define NSLOT 18     // ws B-fragment slots: 2 kv + 8 wg + 8 wo
#define O_OFF 32768  // byte offset of o[] in d_ws

typedef __attribute__((ext_vector_type(4))) float f4;
typedef __attribute__((ext_vector_type(4))) unsigned u4;
typedef __attribute__((ext_vector_type(2))) unsigned u2;
typedef __attribute__((ext_vector_type(8))) short s8;

__device__ __forceinline__ short f2bf(float f) {
  unsigned u = __builtin_bit_cast(unsigned, f);
  u += 0x7fffu + ((u >> 16) & 1u);   // round-to-nearest-even
  return (short)(u >> 16);
}
__device__ __forceinline__ unsigned cvtpk(float lo, float hi) {
  unsigned r;
  asm("v_cvt_pk_bf16_f32 %0, %1, %2" : "=v"(r) : "v"(lo), "v"(hi));
  return r;
}
__device__ __forceinline__ float bflo(unsigned u) { return __builtin_bit_cast(float, u << 16); }
__device__ __forceinline__ float bfhi(unsigned u) { return __builtin_bit_cast(float, u & 0xffff0000u); }

// swizzled byte offset within a [16][64] bf16 tile (128 B row stride)
__device__ __forceinline__ int swz(int r, int c) {
  return ((r << 7) + (c << 1)) ^ ((r & 7) << 4);
}
// kv tile: [512][16] bf16 (32 B rows); XOR bit4 keyed on row bit2
__device__ __forceinline__ int kvaddr(int r, int c) {
  return ((r << 5) + (c << 1)) ^ ((r & 4) << 2);
}

// ---- prep: pre-format bf16 B-fragments (lane-ordered) into d_ws ----
// slots: 0..1 = kv (ks); 2..9 = wg (ks*4+nt); 10..17 = wo (ks*4+nt)
// wg/wo COLUMN-PERMUTED: slot-nt lane-col holds W[k][4*col+nt].
__global__ void prep_kernel(const float* __restrict__ Wk, const float* __restrict__ Wv,
                            const float* __restrict__ Wg, const float* __restrict__ Wo,
                            short* __restrict__ ws) {
  for (int i = threadIdx.x; i < NSLOT * 64; i += blockDim.x) {
    const int slot = i >> 6, lane = i & 63;
    const int col = lane & 15, kq = (lane >> 4) * 8;
    s8 f;
    if (slot < 2) {
      #pragma unroll
      for (int jj = 0; jj < 8; ++jj) {
        const int k = slot * 32 + kq + jj;
        f[jj] = f2bf(col < 8 ? Wk[k * 8 + col] : Wv[k * 8 + col - 8]);
      }
    } else if (slot < 10) {
      const int idx = slot - 2, ks = idx >> 2, nt = idx & 3;
      #pragma unroll
      for (int jj = 0; jj < 8; ++jj) {
        const int k = ks * 32 + kq + jj;
        f[jj] = f2bf(Wg[k * 64 + 4 * col + nt]);
      }
    } else {
      const int idx = slot - 10, ks = idx >> 2, nt = idx & 3;
      #pragma unroll
      for (int jj = 0; jj < 8; ++jj) {
        const int k = ks * 32 + kq + jj;
        f[jj] = f2bf(Wo[k * 64 + 4 * col + nt]);
      }
    }
    *reinterpret_cast<s8*>(ws + (size_t)i * 8) = f;
  }
}

// ======== K1: pool + K/V GEMM + attention -> o[s][64] (fp32). Pure-read stream.
__global__ __launch_bounds__(512, 6)
void k1_attn(const float* __restrict__ gm, const float* __restrict__ gmask,
             const float* __restrict__ Wq, const short* __restrict__ ws,
             float* __restrict__ o_out)
{
  __shared__ unsigned short kvb_s[NR * 16];  // 16 KB
  __shared__ float maskb[NR];                // 2 KB
  __shared__ float red[8][ND];               // 2 KB
  // 20.25 KB -> 4 blocks/CU (thread-capped), 32 waves

  const int t    = threadIdx.x;
  const int lane = t & 63;
  const int wv   = t >> 6;
  const int arow = lane & 15;
  const int g    = lane >> 4;
  const int kq   = g * 8;
  const int s    = blockIdx.x;

  const f4 zf = {0, 0, 0, 0};
  const float* mrow = gm + (size_t)s * NR * ND;

  for (int i = t; i < NR; i += 512) maskb[i] = gmask[(size_t)s * NR + i];
  const s8 kf0 = *reinterpret_cast<const s8*>(ws + (size_t)(0 * 64 + lane) * 8);
  const s8 kf1 = *reinterpret_cast<const s8*>(ws + (size_t)(1 * 64 + lane) * 8);
  __syncthreads();

  // ---- phase A: stream m, masked pool, K/V GEMM ----
  f4 pl0 = zf, pl1 = zf, pl2 = zf, pl3 = zf;
  #pragma unroll
  for (int mt = 0; mt < 4; ++mt) {
    const int row = wv * 64 + mt * 16 + arow;
    const float mk = maskb[row];
    const float* p = mrow + row * ND + kq;
    const f4 a0 = *reinterpret_cast<const f4*>(p);
    const f4 a1 = *reinterpret_cast<const f4*>(p + 4);
    const f4 b0 = *reinterpret_cast<const f4*>(p + 32);
    const f4 b1 = *reinterpret_cast<const f4*>(p + 36);
    pl0 += a0 * mk; pl1 += a1 * mk; pl2 += b0 * mk; pl3 += b1 * mk;
    u4 ua, ub;
    ua[0] = cvtpk(a0.x, a0.y); ua[1] = cvtpk(a0.z, a0.w);
    ua[2] = cvtpk(a1.x, a1.y); ua[3] = cvtpk(a1.z, a1.w);
    ub[0] = cvtpk(b0.x, b0.y); ub[1] = cvtpk(b0.z, b0.w);
    ub[2] = cvtpk(b1.x, b1.y); ub[3] = cvtpk(b1.z, b1.w);
    const s8 mA = __builtin_bit_cast(s8, ua);
    const s8 mB = __builtin_bit_cast(s8, ub);
    f4 acc = zf;
    acc = __builtin_amdgcn_mfma_f32_16x16x32_bf16(mA, kf0, acc, 0, 0, 0);
    acc = __builtin_amdgcn_mfma_f32_16x16x32_bf16(mB, kf1, acc, 0, 0, 0);
    char* kvb = reinterpret_cast<char*>(&kvb_s[0]);
    const int r0 = wv * 64 + mt * 16;
    #pragma unroll
    for (int q = 0; q < 4; ++q)
      *reinterpret_cast<unsigned short*>(kvb + kvaddr(r0 + g * 4 + q, arow)) =
          (unsigned short)f2bf(acc[q]);
  }
  #pragma unroll
  for (int off = 8; off >= 1; off >>= 1) {
    pl0.x += __shfl_xor(pl0.x, off); pl0.y += __shfl_xor(pl0.y, off);
    pl0.z += __shfl_xor(pl0.z, off); pl0.w += __shfl_xor(pl0.w, off);
    pl1.x += __shfl_xor(pl1.x, off); pl1.y += __shfl_xor(pl1.y, off);
    pl1.z += __shfl_xor(pl1.z, off); pl1.w += __shfl_xor(pl1.w, off);
    pl2.x += __shfl_xor(pl2.x, off); pl2.y += __shfl_xor(pl2.y, off);
    pl2.z += __shfl_xor(pl2.z, off); pl2.w += __shfl_xor(pl2.w, off);
    pl3.x += __shfl_xor(pl3.x, off); pl3.y += __shfl_xor(pl3.y, off);
    pl3.z += __shfl_xor(pl3.z, off); pl3.w += __shfl_xor(pl3.w, off);
  }
  if (arow == 0) {
    *reinterpret_cast<f4*>(&red[wv][kq])          = pl0;
    *reinterpret_cast<f4*>(&red[wv][kq + 4])      = pl1;
    *reinterpret_cast<f4*>(&red[wv][32 + kq])     = pl2;
    *reinterpret_cast<f4*>(&red[wv][32 + kq + 4]) = pl3;
  }
  __syncthreads();

  // ---- per-wave q (redundant all-lane reduce), then attn per head ----
  float q0, q1, q2, q3, q4, q5, q6, q7;
  {
    float qv_l = 0.f;
    #pragma unroll
    for (int p = 0; p < 8; ++p) qv_l += red[p][lane];
    float dn = 0.f;
    #pragma unroll
    for (int i = 0; i < 8; ++i) dn += maskb[lane + 64 * i];
    #pragma unroll
    for (int off = 32; off; off >>= 1) dn += __shfl_xor(dn, off);
    const f4 w0 = *reinterpret_cast<const f4*>(Wq + lane * 64 + wv * 8);
    const f4 w1 = *reinterpret_cast<const f4*>(Wq + lane * 64 + wv * 8 + 4);
    float a0 = qv_l * w0.x, a1 = qv_l * w0.y, a2 = qv_l * w0.z, a3 = qv_l * w0.w;
    float a4 = qv_l * w1.x, a5 = qv_l * w1.y, a6 = qv_l * w1.z, a7 = qv_l * w1.w;
    #pragma unroll
    for (int off = 32; off; off >>= 1) {
      a0 += __shfl_xor(a0, off); a1 += __shfl_xor(a1, off);
      a2 += __shfl_xor(a2, off); a3 += __shfl_xor(a3, off);
      a4 += __shfl_xor(a4, off); a5 += __shfl_xor(a5, off);
      a6 += __shfl_xor(a6, off); a7 += __shfl_xor(a7, off);
    }
    const float qs = 0.35355339059327373f / (dn + 1e-10f);
    q0 = a0 * qs; q1 = a1 * qs; q2 = a2 * qs; q3 = a3 * qs;
    q4 = a4 * qs; q5 = a5 * qs; q6 = a6 * qs; q7 = a7 * qs;
  }
  {
    const char* kvb = reinterpret_cast<const char*>(&kvb_s[0]);
    float lg[8];
    float mx = -3.4e38f;
    #pragma unroll
    for (int i = 0; i < 8; ++i) {
      const int r = lane + 64 * i;
      const u4 kk = *reinterpret_cast<const u4*>(kvb + ((r << 5) ^ ((r & 4) << 2)));
      float acc = q0 * bflo(kk[0]) + q1 * bfhi(kk[0])
                + q2 * bflo(kk[1]) + q3 * bfhi(kk[1])
                + q4 * bflo(kk[2]) + q5 * bfhi(kk[2])
                + q6 * bflo(kk[3]) + q7 * bfhi(kk[3]);
      lg[i] = acc + 1e9f * (maskb[r] - 1.0f);
      mx = fmaxf(mx, lg[i]);
    }
    #pragma unroll
    for (int off = 32; off; off >>= 1) mx = fmaxf(mx, __shfl_xor(mx, off));
    float sum = 0.f;
    #pragma unroll
    for (int i = 0; i < 8; ++i) { lg[i] = __expf(lg[i] - mx); sum += lg[i]; }
    #pragma unroll
    for (int off = 32; off; off >>= 1) sum += __shfl_xor(sum, off);
    const float inv = 1.0f / sum;
    float po[8] = {0, 0, 0, 0, 0, 0, 0, 0};
    #pragma unroll
    for (int i = 0; i < 8; ++i) {
      const int r = lane + 64 * i;
      const float a = lg[i] * inv;
      const u4 vvv = *reinterpret_cast<const u4*>(kvb + (((r << 5) + 16) ^ ((r & 4) << 2)));
      po[0] += a * bflo(vvv[0]); po[1] += a * bfhi(vvv[0]);
      po[2] += a * bflo(vvv[1]); po[3] += a * bfhi(vvv[1]);
      po[4] += a * bflo(vvv[2]); po[5] += a * bfhi(vvv[2]);
      po[6] += a * bflo(vvv[3]); po[7] += a * bfhi(vvv[3]);
    }
    #pragma unroll
    for (int off = 32; off; off >>= 1) {
      #pragma unroll
      for (int c = 0; c < 8; ++c) po[c] += __shfl_xor(po[c], off);
    }
    #pragma unroll
    for (int c = 0; c < 8; ++c)
      if (lane == c) o_out[(size_t)s * ND + wv * 8 + c] = po[c];
  }
}

// ======== K2: gate GEMM + output GEMM. m from L3 (reverse order), nt writes.
__global__ __launch_bounds__(512, 6)
void k2_gate(const float* __restrict__ gm, const float* __restrict__ bgp,
             const float* __restrict__ bop, const short* __restrict__ ws,
             const float* __restrict__ o_in, float* __restrict__ gout)
{
  __shared__ short fragW[16 * 64 * 8];   // 16 KB: wg (0..7), wo (8..15)
  __shared__ short tmpb[8][16 * ND];     // 16 KB per-wave gate tiles
  __shared__ float oflb[ND];             // 256 B
  __shared__ float bgo[2][ND];           // 512 B
  // ~33 KB -> 4 blocks/CU

  const int t    = threadIdx.x;
  const int lane = t & 63;
  const int wv   = t >> 6;
  const int arow = lane & 15;
  const int g    = lane >> 4;
  const int kq   = g * 8;
  // reverse s: consume L3's freshest m lines first (K1 streamed s ascending)
  const int s    = NS - 1 - (int)blockIdx.x;

  const f4 zf = {0, 0, 0, 0};
  const float* mrow = gm + (size_t)s * NR * ND;
  float* orow = gout + (size_t)s * NR * ND;

  for (int i = t; i < 16 * 64; i += 512)
    *reinterpret_cast<s8*>(&fragW[i * 8]) =
        *reinterpret_cast<const s8*>(ws + (size_t)(2 * 64 + i) * 8);
  if (t < 64)       bgo[0][t]      = bgp[t];
  else if (t < 128) bgo[1][t - 64] = bop[t - 64];
  if (t >= 128 && t < 192) oflb[t - 128] = o_in[(size_t)s * ND + (t - 128)];
  __syncthreads();

  const f4 ofv = *reinterpret_cast<const f4*>(&oflb[4 * arow]);
  const f4 bgv = *reinterpret_cast<const f4*>(&bgo[0][4 * arow]);
  const f4 bov = *reinterpret_cast<const f4*>(&bgo[1][4 * arow]);
  short* tmpw = &tmpb[wv][0];

  auto loadB = [&](int mt, f4& a0, f4& a1, f4& b0, f4& b1) {
    const float* p = mrow + (wv * 64 + mt * 16 + arow) * ND + kq;
    a0 = *reinterpret_cast<const f4*>(p);
    a1 = *reinterpret_cast<const f4*>(p + 4);
    b0 = *reinterpret_cast<const f4*>(p + 32);
    b1 = *reinterpret_cast<const f4*>(p + 36);
  };

  auto procB = [&](int mt, f4 a0, f4 a1, f4 b0, f4 b1) {
    const int r0 = wv * 64 + mt * 16;
    u4 ua, ub;
    ua[0] = cvtpk(a0.x, a0.y); ua[1] = cvtpk(a0.z, a0.w);
    ua[2] = cvtpk(a1.x, a1.y); ua[3] = cvtpk(a1.z, a1.w);
    ub[0] = cvtpk(b0.x, b0.y); ub[1] = cvtpk(b0.z, b0.w);
    ub[2] = cvtpk(b1.x, b1.y); ub[3] = cvtpk(b1.z, b1.w);
    const s8 mA = __builtin_bit_cast(s8, ua);
    const s8 mB = __builtin_bit_cast(s8, ub);

    f4 accG[4] = {zf, zf, zf, zf};
    #pragma unroll
    for (int nt = 0; nt < 4; ++nt) {
      const s8 wg0 = *reinterpret_cast<const s8*>(&fragW[((0 + nt) * 64 + lane) * 8]);
      const s8 wg1 = *reinterpret_cast<const s8*>(&fragW[((4 + nt) * 64 + lane) * 8]);
      accG[nt] = __builtin_amdgcn_mfma_f32_16x16x32_bf16(mA, wg0, accG[nt], 0, 0, 0);
      accG[nt] = __builtin_amdgcn_mfma_f32_16x16x32_bf16(mB, wg1, accG[nt], 0, 0, 0);
    }

    #pragma unroll
    for (int q2 = 0; q2 < 4; ++q2) {
      float v[4];
      #pragma unroll
      for (int nt = 0; nt < 4; ++nt) {
        const float e = __expf(-(accG[nt][q2] + bgv[nt]));
        v[nt] = ofv[nt] * __builtin_amdgcn_rcpf(1.0f + e);
      }
      u2 w;
      w[0] = cvtpk(v[0], v[1]);
      w[1] = cvtpk(v[2], v[3]);
      *reinterpret_cast<u2*>(reinterpret_cast<char*>(tmpw) + swz(g * 4 + q2, 4 * arow)) = w;
    }
    asm volatile("s_waitcnt lgkmcnt(0)" ::: "memory");
    __builtin_amdgcn_sched_barrier(0);

    f4 accO[4] = {zf, zf, zf, zf};
    #pragma unroll
    for (int ks = 0; ks < 2; ++ks) {
      const s8 aF = *reinterpret_cast<const s8*>(
          reinterpret_cast<const char*>(tmpw) + swz(arow, ks * 32 + kq));
      #pragma unroll
      for (int nt = 0; nt < 4; ++nt) {
        const s8 woF = *reinterpret_cast<const s8*>(&fragW[((8 + ks * 4 + nt) * 64 + lane) * 8]);
        accO[nt] = __builtin_amdgcn_mfma_f32_16x16x32_bf16(aF, woF, accO[nt], 0, 0, 0);
      }
    }
    #pragma unroll
    for (int q2 = 0; q2 < 4; ++q2) {
      f4 ov;
      ov.x = accO[0][q2] + bov.x;
      ov.y = accO[1][q2] + bov.y;
      ov.z = accO[2][q2] + bov.z;
      ov.w = accO[3][q2] + bov.w;
      __builtin_nontemporal_store(
          ov, reinterpret_cast<f4*>(orow + (r0 + g * 4 + q2) * ND + 4 * arow));
    }
  };

  f4 c0, c1, c2, c3, n0, n1, n2, n3;
  loadB(0, c0, c1, c2, c3);
  loadB(1, n0, n1, n2, n3); procB(0, c0, c1, c2, c3);
  loadB(2, c0, c1, c2, c3); procB(1, n0, n1, n2, n3);
  loadB(3, n0, n1, n2, n3); procB(2, c0, c1, c2, c3);
  procB(3, n0, n1, n2, n3);
}

extern "C" void kernel_launch(void* const* d_in, const int* in_sizes, int n_in,
                              void* d_out, int out_size, void* d_ws, size_t ws_size,
                              hipStream_t stream) {
  const float* m    = (const float*)d_in[0];
  const float* mask = (const float*)d_in[1];
  const float* Wq   = (const float*)d_in[2];
  const float* Wk   = (const float*)d_in[3];
  const float* Wv   = (const float*)d_in[4];
  const float* Wg   = (const float*)d_in[5];
  const float* bg   = (const float*)d_in[6];
  const float* Wo   = (const float*)d_in[7];
  const float* bo   = (const float*)d_in[8];
  float* out = (float*)d_out;
  short* ws  = (short*)d_ws;
  float* o_buf = (float*)((char*)d_ws + O_OFF);   // 2048*64 fp32 = 512 KB

  prep_kernel<<<dim3(1), dim3(512), 0, stream>>>(Wk, Wv, Wg, Wo, ws);
  k1_attn<<<dim3(NS), dim3(512), 0, stream>>>(m, mask, Wq, ws, o_buf);
  k2_gate<<<dim3(NS), dim3(512), 0, stream>>>(m, bg, bo, ws, o_buf, out);
}

// Round 13
// 139.802 us; speedup vs baseline: 1.1381x; 1.1381x over previous
//
#include <hip/hip_runtime.h>
#include <hip/hip_bf16.h>
#include <math.h>

#define NS 2048
#define NR 512
#define ND 64
#define NH 8
#define NSLOT 18   // B-fragment slots in ws: 2 kv + 8 wg + 8 wo

typedef __attribute__((ext_vector_type(4))) float f4;
typedef __attribute__((ext_vector_type(4))) unsigned u4;
typedef __attribute__((ext_vector_type(2))) unsigned u2;
typedef __attribute__((ext_vector_type(8))) short s8;

__device__ __forceinline__ short f2bf(float f) {
  unsigned u = __builtin_bit_cast(unsigned, f);
  u += 0x7fffu + ((u >> 16) & 1u);   // round-to-nearest-even
  return (short)(u >> 16);
}
__device__ __forceinline__ unsigned cvtpk(float lo, float hi) {
  unsigned r;
  asm("v_cvt_pk_bf16_f32 %0, %1, %2" : "=v"(r) : "v"(lo), "v"(hi));
  return r;
}
__device__ __forceinline__ float bflo(unsigned u) { return __builtin_bit_cast(float, u << 16); }
__device__ __forceinline__ float bfhi(unsigned u) { return __builtin_bit_cast(float, u & 0xffff0000u); }

// swizzled byte offset within a [16][64] bf16 tile (128 B row stride)
__device__ __forceinline__ int swz(int r, int c) {
  return ((r << 7) + (c << 1)) ^ ((r & 7) << 4);
}
// kv tile: [512][16] bf16 (32 B rows); XOR bit4 keyed on row bit2
__device__ __forceinline__ int kvaddr(int r, int c) {
  return ((r << 5) + (c << 1)) ^ ((r & 4) << 2);
}

// ---- prep: pre-format bf16 B-fragments (lane-ordered) into d_ws ----
// slots: 0..1 = kv (ks); 2..9 = wg (ks*4+nt); 10..17 = wo (ks*4+nt)
// wg/wo COLUMN-PERMUTED: slot-nt lane-col holds W[k][4*col+nt].
__global__ void prep_kernel(const float* __restrict__ Wk, const float* __restrict__ Wv,
                            const float* __restrict__ Wg, const float* __restrict__ Wo,
                            short* __restrict__ ws) {
  for (int i = threadIdx.x; i < NSLOT * 64; i += blockDim.x) {
    const int slot = i >> 6, lane = i & 63;
    const int col = lane & 15, kq = (lane >> 4) * 8;
    s8 f;
    if (slot < 2) {
      #pragma unroll
      for (int jj = 0; jj < 8; ++jj) {
        const int k = slot * 32 + kq + jj;
        f[jj] = f2bf(col < 8 ? Wk[k * 8 + col] : Wv[k * 8 + col - 8]);
      }
    } else if (slot < 10) {
      const int idx = slot - 2, ks = idx >> 2, nt = idx & 3;
      #pragma unroll
      for (int jj = 0; jj < 8; ++jj) {
        const int k = ks * 32 + kq + jj;
        f[jj] = f2bf(Wg[k * 64 + 4 * col + nt]);
      }
    } else {
      const int idx = slot - 10, ks = idx >> 2, nt = idx & 3;
      #pragma unroll
      for (int jj = 0; jj < 8; ++jj) {
        const int k = ks * 32 + kq + jj;
        f[jj] = f2bf(Wo[k * 64 + 4 * col + nt]);
      }
    }
    *reinterpret_cast<s8*>(ws + (size_t)i * 8) = f;
  }
}

__global__ __launch_bounds__(512, 6)
void ga_kernel(const float* __restrict__ gm, const float* __restrict__ gmask,
               const float* __restrict__ Wq, const float* __restrict__ bgp,
               const float* __restrict__ bop, const short* __restrict__ ws,
               float* __restrict__ gout)
{
  __shared__ short fragB[NSLOT * 64 * 8];          // 18 KB
  __shared__ union {
    unsigned short kv[NR][16];                     // 16 KB (phase A/attention)
    short tmp[8][16 * ND];                         // 16 KB (phase B, per-wave)
  } ukv;
  __shared__ float maskb[NR];                      // 2 KB
  __shared__ float red[8][ND];                     // 2 KB pool partials
  __shared__ float ofl[ND];                        // 256 B
  __shared__ float bgo[2][ND];                     // 512 B staged bg, bo
  // total 39936 B -> 4 blocks/CU

  const int t    = threadIdx.x;
  const int lane = t & 63;
  const int wv   = t >> 6;
  const int s    = blockIdx.x;

  const int arow = lane & 15;   // A-frag row / D col
  const int g    = lane >> 4;   // k-quad group
  const int kq   = g * 8;

  const float* mrow = gm + (size_t)s * NR * ND;

  // ---- stage 0: mask + kv-frag slots only (wg/wo staged later, under attn) --
  for (int i = t; i < NR; i += 512) maskb[i] = gmask[(size_t)s * NR + i];
  if (t < 128)
    *reinterpret_cast<s8*>(&fragB[t * 8]) =
        *reinterpret_cast<const s8*>(ws + (size_t)t * 8);
  __syncthreads();   // B1

  // ---- phase A: stream m; fp32 masked pool; K/V GEMM (convert inline) ----
  f4 pA0 = {0,0,0,0}, pA1 = {0,0,0,0}, pB0 = {0,0,0,0}, pB1 = {0,0,0,0};
  #pragma unroll
  for (int mt = 0; mt < 4; ++mt) {
    const int row = wv * 64 + mt * 16 + arow;
    const float mk = maskb[row];
    const float* p = mrow + row * ND + kq;
    const f4 a0 = *reinterpret_cast<const f4*>(p);
    const f4 a1 = *reinterpret_cast<const f4*>(p + 4);
    const f4 b0 = *reinterpret_cast<const f4*>(p + 32);
    const f4 b1 = *reinterpret_cast<const f4*>(p + 36);
    pA0 += a0 * mk; pA1 += a1 * mk; pB0 += b0 * mk; pB1 += b1 * mk;
    u4 ua, ub;
    ua[0] = cvtpk(a0.x, a0.y); ua[1] = cvtpk(a0.z, a0.w);
    ua[2] = cvtpk(a1.x, a1.y); ua[3] = cvtpk(a1.z, a1.w);
    ub[0] = cvtpk(b0.x, b0.y); ub[1] = cvtpk(b0.z, b0.w);
    ub[2] = cvtpk(b1.x, b1.y); ub[3] = cvtpk(b1.z, b1.w);
    const s8 mA = __builtin_bit_cast(s8, ua);
    const s8 mB = __builtin_bit_cast(s8, ub);
    const s8 kf0 = *reinterpret_cast<const s8*>(&fragB[(0 * 64 + lane) * 8]);
    const s8 kf1 = *reinterpret_cast<const s8*>(&fragB[(1 * 64 + lane) * 8]);
    f4 acc = {0,0,0,0};
    acc = __builtin_amdgcn_mfma_f32_16x16x32_bf16(mA, kf0, acc, 0, 0, 0);
    acc = __builtin_amdgcn_mfma_f32_16x16x32_bf16(mB, kf1, acc, 0, 0, 0);
    const int r0 = wv * 64 + mt * 16;
    #pragma unroll
    for (int q = 0; q < 4; ++q)
      *reinterpret_cast<unsigned short*>(
          reinterpret_cast<char*>(ukv.kv) + kvaddr(r0 + g * 4 + q, arow)) =
          (unsigned short)f2bf(acc[q]);
  }
  // reduce pool over the 16 rows spread across lanes differing in lane&15
  #pragma unroll
  for (int off = 8; off >= 1; off >>= 1) {
    pA0.x += __shfl_xor(pA0.x, off); pA0.y += __shfl_xor(pA0.y, off);
    pA0.z += __shfl_xor(pA0.z, off); pA0.w += __shfl_xor(pA0.w, off);
    pA1.x += __shfl_xor(pA1.x, off); pA1.y += __shfl_xor(pA1.y, off);
    pA1.z += __shfl_xor(pA1.z, off); pA1.w += __shfl_xor(pA1.w, off);
    pB0.x += __shfl_xor(pB0.x, off); pB0.y += __shfl_xor(pB0.y, off);
    pB0.z += __shfl_xor(pB0.z, off); pB0.w += __shfl_xor(pB0.w, off);
    pB1.x += __shfl_xor(pB1.x, off); pB1.y += __shfl_xor(pB1.y, off);
    pB1.z += __shfl_xor(pB1.z, off); pB1.w += __shfl_xor(pB1.w, off);
  }
  if (arow == 0) {
    *reinterpret_cast<f4*>(&red[wv][kq])          = pA0;
    *reinterpret_cast<f4*>(&red[wv][kq + 4])      = pA1;
    *reinterpret_cast<f4*>(&red[wv][32 + kq])     = pB0;
    *reinterpret_cast<f4*>(&red[wv][32 + kq + 4]) = pB1;
  }
  __syncthreads();   // B2: kv + red ready

  // ---- staged under attn: wg/wo fragments + bg/bo (read only after B3) ----
  for (int i = t; i < 16 * 64; i += 512)
    *reinterpret_cast<s8*>(&fragB[(128 + i) * 8]) =
        *reinterpret_cast<const s8*>(ws + (size_t)(128 + i) * 8);
  if (t < 64)            bgo[0][t]      = bgp[t];
  else if (t < 128)      bgo[1][t - 64] = bop[t - 64];

  // ---- prefetch phase-B tile 0 (hides HBM/L3 latency under q+attention) ----
  f4 c0, c1, c2, c3, n0, n1, n2, n3;
  {
    const float* p = mrow + (wv * 64 + arow) * ND + kq;
    c0 = *reinterpret_cast<const f4*>(p);
    c1 = *reinterpret_cast<const f4*>(p + 4);
    c2 = *reinterpret_cast<const f4*>(p + 32);
    c3 = *reinterpret_cast<const f4*>(p + 36);
  }

  // ---- per-wave redundant q: pool-normalize, @Wq, scale (no barriers) ----
  float q0, q1, q2, q3, q4, q5, q6, q7;
  {
    float qv_l = 0.f;
    #pragma unroll
    for (int p = 0; p < 8; ++p) qv_l += red[p][lane];
    float dn = 0.f;
    #pragma unroll
    for (int i = 0; i < 8; ++i) dn += maskb[lane + 64 * i];
    #pragma unroll
    for (int off = 32; off; off >>= 1) dn += __shfl_xor(dn, off);
    const f4 w0 = *reinterpret_cast<const f4*>(Wq + lane * 64 + wv * 8);
    const f4 w1 = *reinterpret_cast<const f4*>(Wq + lane * 64 + wv * 8 + 4);
    float a0 = qv_l * w0.x, a1 = qv_l * w0.y, a2 = qv_l * w0.z, a3 = qv_l * w0.w;
    float a4 = qv_l * w1.x, a5 = qv_l * w1.y, a6 = qv_l * w1.z, a7 = qv_l * w1.w;
    #pragma unroll
    for (int off = 32; off; off >>= 1) {
      a0 += __shfl_xor(a0, off); a1 += __shfl_xor(a1, off);
      a2 += __shfl_xor(a2, off); a3 += __shfl_xor(a3, off);
      a4 += __shfl_xor(a4, off); a5 += __shfl_xor(a5, off);
      a6 += __shfl_xor(a6, off); a7 += __shfl_xor(a7, off);
    }
    const float qs = 0.35355339059327373f / (dn + 1e-10f);
    q0 = a0 * qs; q1 = a1 * qs; q2 = a2 * qs; q3 = a3 * qs;
    q4 = a4 * qs; q5 = a5 * qs; q6 = a6 * qs; q7 = a7 * qs;
  }

  // ---- logits + softmax + PV in registers: wave wv owns head wv ----
  {
    float lg[8];
    float mx = -3.4e38f;
    #pragma unroll
    for (int i = 0; i < 8; ++i) {
      const int r = lane + 64 * i;
      const u4 kk = *reinterpret_cast<const u4*>(
          reinterpret_cast<const char*>(ukv.kv) + ((r << 5) ^ ((r & 4) << 2)));
      float acc = q0 * bflo(kk[0]) + q1 * bfhi(kk[0])
                + q2 * bflo(kk[1]) + q3 * bfhi(kk[1])
                + q4 * bflo(kk[2]) + q5 * bfhi(kk[2])
                + q6 * bflo(kk[3]) + q7 * bfhi(kk[3]);
      lg[i] = acc + 1e9f * (maskb[r] - 1.0f);
      mx = fmaxf(mx, lg[i]);
    }
    #pragma unroll
    for (int off = 32; off; off >>= 1) mx = fmaxf(mx, __shfl_xor(mx, off));
    float sum = 0.f;
    #pragma unroll
    for (int i = 0; i < 8; ++i) { lg[i] = __expf(lg[i] - mx); sum += lg[i]; }
    #pragma unroll
    for (int off = 32; off; off >>= 1) sum += __shfl_xor(sum, off);
    const float inv = 1.0f / sum;
    float po[8] = {0,0,0,0,0,0,0,0};
    #pragma unroll
    for (int i = 0; i < 8; ++i) {
      const int r = lane + 64 * i;
      const float a = lg[i] * inv;
      const u4 vvv = *reinterpret_cast<const u4*>(
          reinterpret_cast<const char*>(ukv.kv) + (((r << 5) + 16) ^ ((r & 4) << 2)));
      po[0] += a * bflo(vvv[0]); po[1] += a * bfhi(vvv[0]);
      po[2] += a * bflo(vvv[1]); po[3] += a * bfhi(vvv[1]);
      po[4] += a * bflo(vvv[2]); po[5] += a * bfhi(vvv[2]);
      po[6] += a * bflo(vvv[3]); po[7] += a * bfhi(vvv[3]);
    }
    #pragma unroll
    for (int off = 32; off; off >>= 1) {
      #pragma unroll
      for (int c = 0; c < 8; ++c) po[c] += __shfl_xor(po[c], off);
    }
    #pragma unroll
    for (int c = 0; c < 8; ++c) if (lane == c) ofl[wv * 8 + c] = po[c];
  }
  __syncthreads();   // B3: ofl + wg/wo + bgo ready; kv dead -> tmp usable

  // ---- phase B: 1-deep register-pipelined; rcp sigmoid; nt stores ----
  short* tmpw = &ukv.tmp[wv][0];
  float* orow_base = gout + (size_t)s * NR * ND;
  const f4 zf = {0,0,0,0};
  const f4 ofv = *reinterpret_cast<const f4*>(&ofl[4 * arow]);
  const f4 bgv = *reinterpret_cast<const f4*>(&bgo[0][4 * arow]);
  const f4 bov = *reinterpret_cast<const f4*>(&bgo[1][4 * arow]);

  auto loadB = [&](int mt, f4& a0, f4& a1, f4& b0, f4& b1) {
    const float* p = mrow + (wv * 64 + mt * 16 + arow) * ND + kq;
    a0 = *reinterpret_cast<const f4*>(p);
    a1 = *reinterpret_cast<const f4*>(p + 4);
    b0 = *reinterpret_cast<const f4*>(p + 32);
    b1 = *reinterpret_cast<const f4*>(p + 36);
  };

  auto procB = [&](int mt, f4 a0, f4 a1, f4 b0, f4 b1) {
    const int r0 = wv * 64 + mt * 16;
    u4 ua, ub;
    ua[0] = cvtpk(a0.x, a0.y); ua[1] = cvtpk(a0.z, a0.w);
    ua[2] = cvtpk(a1.x, a1.y); ua[3] = cvtpk(a1.z, a1.w);
    ub[0] = cvtpk(b0.x, b0.y); ub[1] = cvtpk(b0.z, b0.w);
    ub[2] = cvtpk(b1.x, b1.y); ub[3] = cvtpk(b1.z, b1.w);
    const s8 mA = __builtin_bit_cast(s8, ua);
    const s8 mB = __builtin_bit_cast(s8, ub);

    // G = m_tile @ Wg' (col-permuted)
    f4 accG[4] = {zf, zf, zf, zf};
    __builtin_amdgcn_s_setprio(1);
    #pragma unroll
    for (int nt = 0; nt < 4; ++nt) {
      const s8 wg0 = *reinterpret_cast<const s8*>(&fragB[((2 + nt) * 64 + lane) * 8]);
      const s8 wg1 = *reinterpret_cast<const s8*>(&fragB[((6 + nt) * 64 + lane) * 8]);
      accG[nt] = __builtin_amdgcn_mfma_f32_16x16x32_bf16(mA, wg0, accG[nt], 0, 0, 0);
      accG[nt] = __builtin_amdgcn_mfma_f32_16x16x32_bf16(mB, wg1, accG[nt], 0, 0, 0);
    }
    __builtin_amdgcn_s_setprio(0);

    // tmp = o * sigmoid(G + bg) -> bf16 tile; sigmoid via v_rcp (1-ulp)
    #pragma unroll
    for (int q2 = 0; q2 < 4; ++q2) {
      float v[4];
      #pragma unroll
      for (int nt = 0; nt < 4; ++nt) {
        const float e = __expf(-(accG[nt][q2] + bgv[nt]));
        v[nt] = ofv[nt] * __builtin_amdgcn_rcpf(1.0f + e);
      }
      u2 w;
      w[0] = cvtpk(v[0], v[1]);
      w[1] = cvtpk(v[2], v[3]);
      *reinterpret_cast<u2*>(reinterpret_cast<char*>(tmpw) + swz(g * 4 + q2, 4 * arow)) = w;
    }
    asm volatile("s_waitcnt lgkmcnt(0)" ::: "memory");
    __builtin_amdgcn_sched_barrier(0);

    // OUT = tmp @ Wo' + bo ; nt dwordx4 stores (bypass L3 so m stays cached)
    f4 accO[4] = {zf, zf, zf, zf};
    __builtin_amdgcn_s_setprio(1);
    #pragma unroll
    for (int ks = 0; ks < 2; ++ks) {
      const s8 aF = *reinterpret_cast<const s8*>(
          reinterpret_cast<const char*>(tmpw) + swz(arow, ks * 32 + kq));
      #pragma unroll
      for (int nt = 0; nt < 4; ++nt) {
        const s8 woF = *reinterpret_cast<const s8*>(&fragB[((10 + ks * 4 + nt) * 64 + lane) * 8]);
        accO[nt] = __builtin_amdgcn_mfma_f32_16x16x32_bf16(aF, woF, accO[nt], 0, 0, 0);
      }
    }
    __builtin_amdgcn_s_setprio(0);
    #pragma unroll
    for (int q2 = 0; q2 < 4; ++q2) {
      f4 ov;
      ov.x = accO[0][q2] + bov.x;
      ov.y = accO[1][q2] + bov.y;
      ov.z = accO[2][q2] + bov.z;
      ov.w = accO[3][q2] + bov.w;
      __builtin_nontemporal_store(
          ov, reinterpret_cast<f4*>(orow_base + (r0 + g * 4 + q2) * ND + 4 * arow));
    }
  };

  loadB(1, n0, n1, n2, n3); procB(0, c0, c1, c2, c3);
  loadB(2, c0, c1, c2, c3); procB(1, n0, n1, n2, n3);
  loadB(3, n0, n1, n2, n3); procB(2, c0, c1, c2, c3);
  procB(3, n0, n1, n2, n3);
}

extern "C" void kernel_launch(void* const* d_in, const int* in_sizes, int n_in,
                              void* d_out, int out_size, void* d_ws, size_t ws_size,
                              hipStream_t stream) {
  const float* m    = (const float*)d_in[0];
  const float* mask = (const float*)d_in[1];
  const float* Wq   = (const float*)d_in[2];
  const float* Wk   = (const float*)d_in[3];
  const float* Wv   = (const float*)d_in[4];
  const float* Wg   = (const float*)d_in[5];
  const float* bg   = (const float*)d_in[6];
  const float* Wo   = (const float*)d_in[7];
  const float* bo   = (const float*)d_in[8];
  float* out = (float*)d_out;
  short* ws  = (short*)d_ws;

  prep_kernel<<<dim3(1), dim3(512), 0, stream>>>(Wk, Wv, Wg, Wo, ws);
  ga_kernel<<<dim3(NS), dim3(512), 0, stream>>>(m, mask, Wq, bg, bo, ws, out);
}

// Round 14
// 136.329 us; speedup vs baseline: 1.1671x; 1.0255x over previous
//
#include <hip/hip_runtime.h>
#include <hip/hip_bf16.h>
#include <math.h>

#define NS 2048
#define NR 512
#define ND 64
#define NH 8
#define NSLOT 18   // B-fragment slots in ws: 2 kv + 8 wg + 8 wo

typedef __attribute__((ext_vector_type(4))) float f4;
typedef __attribute__((ext_vector_type(4))) unsigned u4;
typedef __attribute__((ext_vector_type(2))) unsigned u2;
typedef __attribute__((ext_vector_type(8))) short s8;

__device__ __forceinline__ short f2bf(float f) {
  unsigned u = __builtin_bit_cast(unsigned, f);
  u += 0x7fffu + ((u >> 16) & 1u);   // round-to-nearest-even
  return (short)(u >> 16);
}
__device__ __forceinline__ unsigned cvtpk(float lo, float hi) {
  unsigned r;
  asm("v_cvt_pk_bf16_f32 %0, %1, %2" : "=v"(r) : "v"(lo), "v"(hi));
  return r;
}
__device__ __forceinline__ float bflo(unsigned u) { return __builtin_bit_cast(float, u << 16); }
__device__ __forceinline__ float bfhi(unsigned u) { return __builtin_bit_cast(float, u & 0xffff0000u); }

// swizzled byte offset within a [16][64] bf16 tile (128 B row stride)
__device__ __forceinline__ int swz(int r, int c) {
  return ((r << 7) + (c << 1)) ^ ((r & 7) << 4);
}
// kv tile: [512][16] bf16 (32 B rows); XOR bit4 keyed on row bit2
__device__ __forceinline__ int kvaddr(int r, int c) {
  return ((r << 5) + (c << 1)) ^ ((r & 4) << 2);
}

// ---- prep: pre-format bf16 B-fragments (lane-ordered) into d_ws ----
// slots: 0..1 = kv (ks); 2..9 = wg (ks*4+nt); 10..17 = wo (ks*4+nt)
// wg/wo COLUMN-PERMUTED: slot-nt lane-col holds W[k][4*col+nt].
__global__ void prep_kernel(const float* __restrict__ Wk, const float* __restrict__ Wv,
                            const float* __restrict__ Wg, const float* __restrict__ Wo,
                            short* __restrict__ ws) {
  for (int i = threadIdx.x; i < NSLOT * 64; i += blockDim.x) {
    const int slot = i >> 6, lane = i & 63;
    const int col = lane & 15, kq = (lane >> 4) * 8;
    s8 f;
    if (slot < 2) {
      #pragma unroll
      for (int jj = 0; jj < 8; ++jj) {
        const int k = slot * 32 + kq + jj;
        f[jj] = f2bf(col < 8 ? Wk[k * 8 + col] : Wv[k * 8 + col - 8]);
      }
    } else if (slot < 10) {
      const int idx = slot - 2, ks = idx >> 2, nt = idx & 3;
      #pragma unroll
      for (int jj = 0; jj < 8; ++jj) {
        const int k = ks * 32 + kq + jj;
        f[jj] = f2bf(Wg[k * 64 + 4 * col + nt]);
      }
    } else {
      const int idx = slot - 10, ks = idx >> 2, nt = idx & 3;
      #pragma unroll
      for (int jj = 0; jj < 8; ++jj) {
        const int k = ks * 32 + kq + jj;
        f[jj] = f2bf(Wo[k * 64 + 4 * col + nt]);
      }
    }
    *reinterpret_cast<s8*>(ws + (size_t)i * 8) = f;
  }
}

__global__ __launch_bounds__(512, 6)
void ga_kernel(const float* __restrict__ gm, const float* __restrict__ gmask,
               const float* __restrict__ Wq, const float* __restrict__ bgp,
               const float* __restrict__ bop, const short* __restrict__ ws,
               float* __restrict__ gout)
{
  __shared__ short fragB[NSLOT * 64 * 8];          // 18 KB
  __shared__ union {
    unsigned short kv[NR][16];                     // 16 KB (phase A/attention)
    short tmp[8][16 * ND];                         // 16 KB (phase B, per-wave)
  } ukv;
  __shared__ float maskb[NR];                      // 2 KB
  __shared__ float red[8][ND];                     // 2 KB pool partials
  __shared__ float ofl[ND];                        // 256 B
  __shared__ float bgo[2][ND];                     // 512 B staged bg, bo
  // total 39936 B -> 4 blocks/CU

  const int t    = threadIdx.x;
  const int lane = t & 63;
  const int wv   = t >> 6;
  const int s    = blockIdx.x;

  const int arow = lane & 15;   // A-frag row / D col
  const int g    = lane >> 4;   // k-quad group
  const int kq   = g * 8;

  const float* mrow = gm + (size_t)s * NR * ND;

  // ---- stage 0: mask + fragB + bg/bo -> LDS ----
  for (int i = t; i < NR; i += 512) maskb[i] = gmask[(size_t)s * NR + i];
  for (int i = t; i < NSLOT * 64; i += 512)
    *reinterpret_cast<s8*>(&fragB[i * 8]) =
        *reinterpret_cast<const s8*>(ws + (size_t)i * 8);
  if (t < 64)            bgo[0][t]      = bgp[t];
  else if (t < 128)      bgo[1][t - 64] = bop[t - 64];
  __syncthreads();   // B1

  // ---- phase A: stream m; fp32 masked pool; K/V GEMM (convert inline) ----
  f4 pA0 = {0,0,0,0}, pA1 = {0,0,0,0}, pB0 = {0,0,0,0}, pB1 = {0,0,0,0};
  #pragma unroll
  for (int mt = 0; mt < 4; ++mt) {
    const int row = wv * 64 + mt * 16 + arow;
    const float mk = maskb[row];
    const float* p = mrow + row * ND + kq;
    const f4 a0 = *reinterpret_cast<const f4*>(p);
    const f4 a1 = *reinterpret_cast<const f4*>(p + 4);
    const f4 b0 = *reinterpret_cast<const f4*>(p + 32);
    const f4 b1 = *reinterpret_cast<const f4*>(p + 36);
    pA0 += a0 * mk; pA1 += a1 * mk; pB0 += b0 * mk; pB1 += b1 * mk;
    u4 ua, ub;
    ua[0] = cvtpk(a0.x, a0.y); ua[1] = cvtpk(a0.z, a0.w);
    ua[2] = cvtpk(a1.x, a1.y); ua[3] = cvtpk(a1.z, a1.w);
    ub[0] = cvtpk(b0.x, b0.y); ub[1] = cvtpk(b0.z, b0.w);
    ub[2] = cvtpk(b1.x, b1.y); ub[3] = cvtpk(b1.z, b1.w);
    const s8 mA = __builtin_bit_cast(s8, ua);
    const s8 mB = __builtin_bit_cast(s8, ub);
    const s8 kf0 = *reinterpret_cast<const s8*>(&fragB[(0 * 64 + lane) * 8]);
    const s8 kf1 = *reinterpret_cast<const s8*>(&fragB[(1 * 64 + lane) * 8]);
    f4 acc = {0,0,0,0};
    acc = __builtin_amdgcn_mfma_f32_16x16x32_bf16(mA, kf0, acc, 0, 0, 0);
    acc = __builtin_amdgcn_mfma_f32_16x16x32_bf16(mB, kf1, acc, 0, 0, 0);
    const int r0 = wv * 64 + mt * 16;
    #pragma unroll
    for (int q = 0; q < 4; ++q)
      *reinterpret_cast<unsigned short*>(
          reinterpret_cast<char*>(ukv.kv) + kvaddr(r0 + g * 4 + q, arow)) =
          (unsigned short)f2bf(acc[q]);
  }
  // reduce pool over the 16 rows spread across lanes differing in lane&15
  #pragma unroll
  for (int off = 8; off >= 1; off >>= 1) {
    pA0.x += __shfl_xor(pA0.x, off); pA0.y += __shfl_xor(pA0.y, off);
    pA0.z += __shfl_xor(pA0.z, off); pA0.w += __shfl_xor(pA0.w, off);
    pA1.x += __shfl_xor(pA1.x, off); pA1.y += __shfl_xor(pA1.y, off);
    pA1.z += __shfl_xor(pA1.z, off); pA1.w += __shfl_xor(pA1.w, off);
    pB0.x += __shfl_xor(pB0.x, off); pB0.y += __shfl_xor(pB0.y, off);
    pB0.z += __shfl_xor(pB0.z, off); pB0.w += __shfl_xor(pB0.w, off);
    pB1.x += __shfl_xor(pB1.x, off); pB1.y += __shfl_xor(pB1.y, off);
    pB1.z += __shfl_xor(pB1.z, off); pB1.w += __shfl_xor(pB1.w, off);
  }
  if (arow == 0) {
    *reinterpret_cast<f4*>(&red[wv][kq])          = pA0;
    *reinterpret_cast<f4*>(&red[wv][kq + 4])      = pA1;
    *reinterpret_cast<f4*>(&red[wv][32 + kq])     = pB0;
    *reinterpret_cast<f4*>(&red[wv][32 + kq + 4]) = pB1;
  }
  __syncthreads();   // B2: kv + red ready

  // ---- prefetch phase-B tile 0 (hides HBM/L3 latency under q+attention) ----
  f4 c0, c1, c2, c3, n0, n1, n2, n3;
  {
    const float* p = mrow + (wv * 64 + arow) * ND + kq;
    c0 = *reinterpret_cast<const f4*>(p);
    c1 = *reinterpret_cast<const f4*>(p + 4);
    c2 = *reinterpret_cast<const f4*>(p + 32);
    c3 = *reinterpret_cast<const f4*>(p + 36);
  }

  // ---- per-wave redundant q: pool-normalize, @Wq, scale (no barriers) ----
  float q0, q1, q2, q3, q4, q5, q6, q7;
  {
    float qv_l = 0.f;
    #pragma unroll
    for (int p = 0; p < 8; ++p) qv_l += red[p][lane];
    float dn = 0.f;
    #pragma unroll
    for (int i = 0; i < 8; ++i) dn += maskb[lane + 64 * i];
    #pragma unroll
    for (int off = 32; off; off >>= 1) dn += __shfl_xor(dn, off);
    const f4 w0 = *reinterpret_cast<const f4*>(Wq + lane * 64 + wv * 8);
    const f4 w1 = *reinterpret_cast<const f4*>(Wq + lane * 64 + wv * 8 + 4);
    float a0 = qv_l * w0.x, a1 = qv_l * w0.y, a2 = qv_l * w0.z, a3 = qv_l * w0.w;
    float a4 = qv_l * w1.x, a5 = qv_l * w1.y, a6 = qv_l * w1.z, a7 = qv_l * w1.w;
    #pragma unroll
    for (int off = 32; off; off >>= 1) {
      a0 += __shfl_xor(a0, off); a1 += __shfl_xor(a1, off);
      a2 += __shfl_xor(a2, off); a3 += __shfl_xor(a3, off);
      a4 += __shfl_xor(a4, off); a5 += __shfl_xor(a5, off);
      a6 += __shfl_xor(a6, off); a7 += __shfl_xor(a7, off);
    }
    const float qs = 0.35355339059327373f / (dn + 1e-10f);
    q0 = a0 * qs; q1 = a1 * qs; q2 = a2 * qs; q3 = a3 * qs;
    q4 = a4 * qs; q5 = a5 * qs; q6 = a6 * qs; q7 = a7 * qs;
  }

  // ---- logits + softmax + PV in registers: wave wv owns head wv ----
  {
    float lg[8];
    float mx = -3.4e38f;
    #pragma unroll
    for (int i = 0; i < 8; ++i) {
      const int r = lane + 64 * i;
      const u4 kk = *reinterpret_cast<const u4*>(
          reinterpret_cast<const char*>(ukv.kv) + ((r << 5) ^ ((r & 4) << 2)));
      float acc = q0 * bflo(kk[0]) + q1 * bfhi(kk[0])
                + q2 * bflo(kk[1]) + q3 * bfhi(kk[1])
                + q4 * bflo(kk[2]) + q5 * bfhi(kk[2])
                + q6 * bflo(kk[3]) + q7 * bfhi(kk[3]);
      lg[i] = acc + 1e9f * (maskb[r] - 1.0f);
      mx = fmaxf(mx, lg[i]);
    }
    #pragma unroll
    for (int off = 32; off; off >>= 1) mx = fmaxf(mx, __shfl_xor(mx, off));
    float sum = 0.f;
    #pragma unroll
    for (int i = 0; i < 8; ++i) { lg[i] = __expf(lg[i] - mx); sum += lg[i]; }
    #pragma unroll
    for (int off = 32; off; off >>= 1) sum += __shfl_xor(sum, off);
    const float inv = 1.0f / sum;
    float po[8] = {0,0,0,0,0,0,0,0};
    #pragma unroll
    for (int i = 0; i < 8; ++i) {
      const int r = lane + 64 * i;
      const float a = lg[i] * inv;
      const u4 vvv = *reinterpret_cast<const u4*>(
          reinterpret_cast<const char*>(ukv.kv) + (((r << 5) + 16) ^ ((r & 4) << 2)));
      po[0] += a * bflo(vvv[0]); po[1] += a * bfhi(vvv[0]);
      po[2] += a * bflo(vvv[1]); po[3] += a * bfhi(vvv[1]);
      po[4] += a * bflo(vvv[2]); po[5] += a * bfhi(vvv[2]);
      po[6] += a * bflo(vvv[3]); po[7] += a * bfhi(vvv[3]);
    }
    #pragma unroll
    for (int off = 32; off; off >>= 1) {
      #pragma unroll
      for (int c = 0; c < 8; ++c) po[c] += __shfl_xor(po[c], off);
    }
    #pragma unroll
    for (int c = 0; c < 8; ++c) if (lane == c) ofl[wv * 8 + c] = po[c];
  }
  __syncthreads();   // B3: ofl ready; kv dead -> tmp usable

  // ---- phase B: 1-deep register-pipelined; rcp sigmoid; nt stores ----
  short* tmpw = &ukv.tmp[wv][0];
  float* orow_base = gout + (size_t)s * NR * ND;
  const f4 zf = {0,0,0,0};
  const f4 ofv = *reinterpret_cast<const f4*>(&ofl[4 * arow]);
  const f4 bgv = *reinterpret_cast<const f4*>(&bgo[0][4 * arow]);
  const f4 bov = *reinterpret_cast<const f4*>(&bgo[1][4 * arow]);

  auto loadB = [&](int mt, f4& a0, f4& a1, f4& b0, f4& b1) {
    const float* p = mrow + (wv * 64 + mt * 16 + arow) * ND + kq;
    a0 = *reinterpret_cast<const f4*>(p);
    a1 = *reinterpret_cast<const f4*>(p + 4);
    b0 = *reinterpret_cast<const f4*>(p + 32);
    b1 = *reinterpret_cast<const f4*>(p + 36);
  };

  auto procB = [&](int mt, f4 a0, f4 a1, f4 b0, f4 b1) {
    const int r0 = wv * 64 + mt * 16;
    u4 ua, ub;
    ua[0] = cvtpk(a0.x, a0.y); ua[1] = cvtpk(a0.z, a0.w);
    ua[2] = cvtpk(a1.x, a1.y); ua[3] = cvtpk(a1.z, a1.w);
    ub[0] = cvtpk(b0.x, b0.y); ub[1] = cvtpk(b0.z, b0.w);
    ub[2] = cvtpk(b1.x, b1.y); ub[3] = cvtpk(b1.z, b1.w);
    const s8 mA = __builtin_bit_cast(s8, ua);
    const s8 mB = __builtin_bit_cast(s8, ub);

    // G = m_tile @ Wg' (col-permuted)
    f4 accG[4] = {zf, zf, zf, zf};
    #pragma unroll
    for (int nt = 0; nt < 4; ++nt) {
      const s8 wg0 = *reinterpret_cast<const s8*>(&fragB[((2 + nt) * 64 + lane) * 8]);
      const s8 wg1 = *reinterpret_cast<const s8*>(&fragB[((6 + nt) * 64 + lane) * 8]);
      accG[nt] = __builtin_amdgcn_mfma_f32_16x16x32_bf16(mA, wg0, accG[nt], 0, 0, 0);
      accG[nt] = __builtin_amdgcn_mfma_f32_16x16x32_bf16(mB, wg1, accG[nt], 0, 0, 0);
    }

    // tmp = o * sigmoid(G + bg) -> bf16 tile; sigmoid via v_rcp (1-ulp)
    #pragma unroll
    for (int q2 = 0; q2 < 4; ++q2) {
      float v[4];
      #pragma unroll
      for (int nt = 0; nt < 4; ++nt) {
        const float e = __expf(-(accG[nt][q2] + bgv[nt]));
        v[nt] = ofv[nt] * __builtin_amdgcn_rcpf(1.0f + e);
      }
      u2 w;
      w[0] = cvtpk(v[0], v[1]);
      w[1] = cvtpk(v[2], v[3]);
      *reinterpret_cast<u2*>(reinterpret_cast<char*>(tmpw) + swz(g * 4 + q2, 4 * arow)) = w;
    }
    asm volatile("s_waitcnt lgkmcnt(0)" ::: "memory");
    __builtin_amdgcn_sched_barrier(0);

    // OUT = tmp @ Wo' + bo ; nt dwordx4 stores (bypass L3 so m stays cached)
    f4 accO[4] = {zf, zf, zf, zf};
    #pragma unroll
    for (int ks = 0; ks < 2; ++ks) {
      const s8 aF = *reinterpret_cast<const s8*>(
          reinterpret_cast<const char*>(tmpw) + swz(arow, ks * 32 + kq));
      #pragma unroll
      for (int nt = 0; nt < 4; ++nt) {
        const s8 woF = *reinterpret_cast<const s8*>(&fragB[((10 + ks * 4 + nt) * 64 + lane) * 8]);
        accO[nt] = __builtin_amdgcn_mfma_f32_16x16x32_bf16(aF, woF, accO[nt], 0, 0, 0);
      }
    }
    #pragma unroll
    for (int q2 = 0; q2 < 4; ++q2) {
      f4 ov;
      ov.x = accO[0][q2] + bov.x;
      ov.y = accO[1][q2] + bov.y;
      ov.z = accO[2][q2] + bov.z;
      ov.w = accO[3][q2] + bov.w;
      __builtin_nontemporal_store(
          ov, reinterpret_cast<f4*>(orow_base + (r0 + g * 4 + q2) * ND + 4 * arow));
    }
  };

  loadB(1, n0, n1, n2, n3); procB(0, c0, c1, c2, c3);
  loadB(2, c0, c1, c2, c3); procB(1, n0, n1, n2, n3);
  loadB(3, n0, n1, n2, n3); procB(2, c0, c1, c2, c3);
  procB(3, n0, n1, n2, n3);
}

extern "C" void kernel_launch(void* const* d_in, const int* in_sizes, int n_in,
                              void* d_out, int out_size, void* d_ws, size_t ws_size,
                              hipStream_t stream) {
  const float* m    = (const float*)d_in[0];
  const float* mask = (const float*)d_in[1];
  const float* Wq   = (const float*)d_in[2];
  const float* Wk   = (const float*)d_in[3];
  const float* Wv   = (const float*)d_in[4];
  const float* Wg   = (const float*)d_in[5];
  const float* bg   = (const float*)d_in[6];
  const float* Wo   = (const float*)d_in[7];
  const float* bo   = (const float*)d_in[8];
  float* out = (float*)d_out;
  short* ws  = (short*)d_ws;

  prep_kernel<<<dim3(1), dim3(512), 0, stream>>>(Wk, Wv, Wg, Wo, ws);
  ga_kernel<<<dim3(NS), dim3(512), 0, stream>>>(m, mask, Wq, bg, bo, ws, out);
}